// Round 23
// baseline (107.996 us; speedup 1.0000x reference)
//
#include <hip/hip_runtime.h>
#include <math.h>

#define N_TOT 4194304      // 64*256*256
#define CONV_BLOCKS 1024   // 16 co-groups x 64 tiles (32x32)
#define XS_DW 5120         // 1280 chunks x 4 dw (junk: per-row pad + tail)
#define RSTRIDE 148        // LDS row stride (dw)
#define PITCH 272          // padded x row pitch (dwords), 16B aligned
#define PROWS 258          // padded rows (-1..256)
#define PCI (PROWS * PITCH)        // 70176 dwords per channel
#define PAD_TOT (64 * PCI)         // 4491264 dwords
#define PAD_BYTES (PAD_TOT * 4)    // 17965056 B
#define WS_PAD_OFF 32768
#define PAD_GRID (PAD_TOT / 256)   // 17544

__device__ __forceinline__ float sgnf(float x) {
    return x > 0.f ? 1.f : (x < 0.f ? -1.f : 0.f);
}

__device__ __forceinline__ float gelu_f(float v) {
    const float c0 = 0.7978845608028654f;
    float inner = c0 * fmaf(0.044715f * v, v * v, v);
    return 0.5f * v * (1.f + tanhf(inner));
}

// async HBM->LDS. LDS dest = wave-uniform base + lane*width; full waves only.
__device__ __forceinline__ void gll4(const float* g, float* l) {
    __builtin_amdgcn_global_load_lds((const __attribute__((address_space(1))) void*)g,
                                     (__attribute__((address_space(3))) void*)l, 4, 0, 0);
}
__device__ __forceinline__ void gll16(const float* g, float* l) {
    __builtin_amdgcn_global_load_lds((const __attribute__((address_space(1))) void*)g,
                                     (__attribute__((address_space(3))) void*)l, 16, 0, 0);
}

// ---------------------------------------------------------------------------
// Kernel PREP: blocks 0..15 = alpha (4 channels each, 1 wave per channel);
// blocks 16.. = zero-padded copy of x into ws.
// alpha: sign(q*bp) factors; sign(W@(s*v)) = s*sign(W@v) for s=+-1, so the
// 5-iter Hopfield recurrence is pixel-independent: v <- sign(W_c v).
// ---------------------------------------------------------------------------
__global__ __launch_bounds__(256) void prep_kernel(const float* __restrict__ x,
                                                   const float* __restrict__ bp,
                                                   const float* __restrict__ Wm,
                                                   float* __restrict__ alpha,
                                                   float* __restrict__ pad) {
    const int b = blockIdx.x;
    const int tid = threadIdx.x;
    __shared__ float v[4][64];

    if (b < 16) {
        const int g = tid >> 6;               // wave id = channel sub-index
        const int d = tid & 63;
        const int c = b * 4 + g;
        float bpv = bp[c * 64 + d];
        v[g][d] = sgnf(bpv);
        __syncthreads();
        const float* row = Wm + c * 4096 + d * 64;
        for (int it = 0; it < 5; ++it) {
            float s = 0.f;
            #pragma unroll
            for (int e = 0; e < 64; ++e) s = fmaf(row[e], v[g][e], s);
            __syncthreads();
            v[g][d] = sgnf(s);
            __syncthreads();
        }
        float val = bpv * v[g][d];
        #pragma unroll
        for (int off = 32; off; off >>= 1) val += __shfl_down(val, off);
        if (d == 0) alpha[c] = val;
    } else {
        const int idx = (b - 16) * 256 + tid; // < PAD_TOT (exact)
        const int ci = idx / PCI;
        int rem = idx - ci * PCI;
        const int py = rem / PITCH;
        const int px = rem - py * PITCH;
        float val = 0.f;
        if (py >= 1 && py <= 256 && px >= 1 && px <= 256)
            val = x[(ci << 16) + ((py - 1) << 8) + (px - 1)];
        pad[idx] = val;
    }
}

#define LOAD_T(T, XSC, CIOFF)                                                 \
    {                                                                         \
        _Pragma("unroll")                                                     \
        for (int rr = 0; rr < 4; ++rr) {                                      \
            const int off_ = lrow + rr * RSTRIDE + (CIOFF);                   \
            float2 a_ = *reinterpret_cast<const float2*>(&(XSC)[off_]);       \
            float2 b_ = *reinterpret_cast<const float2*>(&(XSC)[off_ + 2]);   \
            T[rr][0] = a_.x; T[rr][1] = a_.y; T[rr][2] = b_.x; T[rr][3] = b_.y;\
        }                                                                     \
    }

#define FMA_CI(T, WP)                                                         \
    {                                                                         \
        _Pragma("unroll")                                                     \
        for (int co = 0; co < 4; ++co) {                                      \
            const float* w_ = (WP) + co * 576;                                \
            _Pragma("unroll")                                                 \
            for (int ky = 0; ky < 3; ++ky)                                    \
                _Pragma("unroll")                                             \
                for (int kx = 0; kx < 3; ++kx) {                              \
                    float wv_ = w_[ky * 3 + kx];                              \
                    _Pragma("unroll")                                         \
                    for (int dy = 0; dy < 2; ++dy)                            \
                        _Pragma("unroll")                                     \
                        for (int j = 0; j < 2; ++j)                           \
                            acc[co][dy][j] = fmaf(wv_, T[dy + ky][kx + j],    \
                                                  acc[co][dy][j]);            \
                }                                                             \
        }                                                                     \
    }

// ---------------------------------------------------------------------------
// Kernel B: 3x3 SAME conv (fp32) + bias + fused y = q + sgn(q)*alpha[c].
// SINGLE-buffered xs = 20480B = exactly 160KB/8 -> 8 blocks/CU at VGPR 52
// (R22's 40960B dbuf capped 4 blocks/CU, 31% occupancy, 42% stall).
// Latency hiding moves from intra-block prefetch to 2x inter-block TLP.
// NOTE launch_bounds(256,2): VGPR cap 128 -- do NOT request 8 (R13's
// mistake: (256,8) forces VGPR 32 -> spill catastrophe).
// ---------------------------------------------------------------------------
__global__ __launch_bounds__(256, 2) void conv_kernel(const float* __restrict__ xp,
                                                      const float* __restrict__ cw,
                                                      const float* __restrict__ cb,
                                                      const float* __restrict__ alpha,
                                                      float* __restrict__ y,
                                                      double* __restrict__ partials) {
    const int tid = threadIdx.x;
    const int b = blockIdx.x;
    const int tile = b & 63;
    const int cog = b >> 6;                   // 4 output channels per group
    const int bx = tile & 7, by = tile >> 3;  // 8x8 tiles of 32x32
    const int tx = tid & 15, ty = tid >> 4;   // cols 2tx,2tx+1; rows 2ty,2ty+1

    __shared__ float xs[XS_DW];               // [r*148 + ci*36 + c] single buf
    double* red = (double*)&xs[5032];         // 8 doubles in junk tail

    int goff[5];
    #pragma unroll
    for (int i = 0; i < 5; ++i) {
        int c4 = i * 256 + tid;               // chunk id < 1280
        int r = c4 / 37;                      // 37 chunks per LDS row
        int rem = c4 - r * 37;
        int ci = rem / 9;
        int cc = rem - ci * 9;
        bool junk = (rem >= 36) || (c4 >= 1258);
        int g = ci * PCI + ((by << 5) + r) * PITCH + (bx << 5) + cc * 4;
        goff[i] = junk ? 0 : g;               // junk chunks read pad base
    }

    float acc[4][2][2];
    #pragma unroll
    for (int co = 0; co < 4; ++co) {
        float bias = cb[cog * 4 + co];
        acc[co][0][0] = bias; acc[co][0][1] = bias;
        acc[co][1][0] = bias; acc[co][1][1] = bias;
    }

    // prologue: stage slab 0
    #pragma unroll
    for (int i = 0; i < 5; ++i)
        gll16(xp + goff[i], &xs[(i * 256 + tid) * 4]);
    __syncthreads();                          // vmcnt drain -> slab 0 ready

    const int lrow = (2 * ty) * RSTRIDE + 2 * tx;
    const float* wbase = cw + cog * 4 * 576;

    float tA[4][4], tB[4][4];

    for (int s = 0; s < 16; ++s) {
        const float* wp = wbase + (s * 4) * 9;

        LOAD_T(tA, xs, 0)
        LOAD_T(tB, xs, 36)
        FMA_CI(tA, wp)
        LOAD_T(tA, xs, 72)
        FMA_CI(tB, wp + 9)
        LOAD_T(tB, xs, 108)
        FMA_CI(tA, wp + 18)
        FMA_CI(tB, wp + 27)

        if (s < 15) {
            __syncthreads();                  // all reads of slab s done
            const float* xb = xp + (s + 1) * (4 * PCI);
            #pragma unroll
            for (int i = 0; i < 5; ++i)
                gll16(xb + goff[i], &xs[(i * 256 + tid) * 4]);
            __syncthreads();                  // staging drained -> slab ready
        }
    }

    // epilogue: y = q + sgn(q)*alpha, aligned float2 stores + f64 sums
    double s1 = 0.0, s2 = 0.0;
    const int gx0 = (bx << 5) + 2 * tx;
    const int gy0 = (by << 5) + 2 * ty;
    #pragma unroll
    for (int co = 0; co < 4; ++co) {
        float a = alpha[cog * 4 + co];
        const int cb_off = (cog * 4 + co) << 16;
        #pragma unroll
        for (int dy = 0; dy < 2; ++dy) {
            float q0 = acc[co][dy][0];
            float q1 = acc[co][dy][1];
            float y0v = q0 + (q0 > 0.f ? a : (q0 < 0.f ? -a : 0.f));
            float y1v = q1 + (q1 > 0.f ? a : (q1 < 0.f ? -a : 0.f));
            float2 pk; pk.x = y0v; pk.y = y1v;
            *reinterpret_cast<float2*>(&y[cb_off + ((gy0 + dy) << 8) + gx0]) = pk;
            s1 += (double)y0v + (double)y1v;
            s2 += (double)y0v * (double)y0v + (double)y1v * (double)y1v;
        }
    }
    #pragma unroll
    for (int off = 32; off; off >>= 1) {
        s1 += __shfl_down(s1, off);
        s2 += __shfl_down(s2, off);
    }
    const int wid = tid >> 6;
    __syncthreads();                          // staging of slab 15 fully done
    if ((tid & 63) == 0) { red[wid * 2] = s1; red[wid * 2 + 1] = s2; }
    __syncthreads();
    if (tid == 0) {
        partials[b * 2]     = red[0] + red[2] + red[4] + red[6];
        partials[b * 2 + 1] = red[1] + red[3] + red[5] + red[7];
    }
}

// ---------------------------------------------------------------------------
// Fallback conv (no padded x) if ws is too small: R15 path.
// ---------------------------------------------------------------------------
__global__ __launch_bounds__(256, 2) void conv_fb(const float* __restrict__ x,
                                                  const float* __restrict__ cw,
                                                  const float* __restrict__ cb,
                                                  const float* __restrict__ alpha,
                                                  const float* __restrict__ zbuf,
                                                  float* __restrict__ y,
                                                  double* __restrict__ partials) {
    const int tid = threadIdx.x;
    const int b = blockIdx.x;
    const int tile = b & 63;
    const int cog = b >> 6;
    const int bx = tile & 7, by = tile >> 3;
    const int tx = tid & 15, ty = tid >> 4;

    __shared__ float xs[2][4864];
    __shared__ double red[4][2];

    int voff[19];
    unsigned vmask = 0u;
    #pragma unroll
    for (int i = 0; i < 19; ++i) {
        int idx = i * 256 + tid;
        int r = idx / 136;
        int rem = idx - r * 136;
        int ci = rem / 34;
        int c = rem - ci * 34;
        int gy = (by << 5) - 1 + r;
        int gx = (bx << 5) + c - 1;
        bool ok = (idx < 4624) && ((unsigned)gy < 256u) && ((unsigned)gx < 256u);
        voff[i] = (ci << 16) + (gy << 8) + gx;
        if (ok) vmask |= (1u << i);
    }

    float acc[4][2][2];
    #pragma unroll
    for (int co = 0; co < 4; ++co) {
        float bias = cb[cog * 4 + co];
        acc[co][0][0] = bias; acc[co][0][1] = bias;
        acc[co][1][0] = bias; acc[co][1][1] = bias;
    }

    #pragma unroll
    for (int i = 0; i < 19; ++i) {
        const float* src = (vmask & (1u << i)) ? (x + voff[i]) : zbuf;
        gll4(src, &xs[0][i * 256 + tid]);
    }
    __syncthreads();

    const int lrow2 = (2 * ty) * 136 + 2 * tx;
    const float* wbase = cw + cog * 4 * 576;

    for (int s = 0; s < 16; ++s) {
        const int cur = s & 1;
        if (s < 15) {
            const float* xb = x + ((s + 1) << 18);
            #pragma unroll
            for (int i = 0; i < 19; ++i) {
                const float* src = (vmask & (1u << i)) ? (xb + voff[i]) : zbuf;
                gll4(src, &xs[cur ^ 1][i * 256 + tid]);
            }
        }
        const float* xsc = xs[cur];
        #pragma unroll
        for (int ci = 0; ci < 4; ++ci) {
            float t[4][4];
            #pragma unroll
            for (int rr = 0; rr < 4; ++rr) {
                const int off = lrow2 + rr * 136 + ci * 34;
                float2 a = *reinterpret_cast<const float2*>(&xsc[off]);
                float2 bb = *reinterpret_cast<const float2*>(&xsc[off + 2]);
                t[rr][0] = a.x; t[rr][1] = a.y; t[rr][2] = bb.x; t[rr][3] = bb.y;
            }
            const float* wp = wbase + (s * 4 + ci) * 9;
            #pragma unroll
            for (int co = 0; co < 4; ++co) {
                const float* w = wp + co * 576;
                #pragma unroll
                for (int ky = 0; ky < 3; ++ky)
                    #pragma unroll
                    for (int kx = 0; kx < 3; ++kx) {
                        float wv = w[ky * 3 + kx];
                        #pragma unroll
                        for (int dy = 0; dy < 2; ++dy)
                            #pragma unroll
                            for (int j = 0; j < 2; ++j)
                                acc[co][dy][j] = fmaf(wv, t[dy + ky][kx + j], acc[co][dy][j]);
                    }
            }
        }
        __syncthreads();
    }

    double s1 = 0.0, s2 = 0.0;
    const int gx0 = (bx << 5) + 2 * tx;
    const int gy0 = (by << 5) + 2 * ty;
    #pragma unroll
    for (int co = 0; co < 4; ++co) {
        float a = alpha[cog * 4 + co];
        const int cb_off = (cog * 4 + co) << 16;
        #pragma unroll
        for (int dy = 0; dy < 2; ++dy) {
            float q0 = acc[co][dy][0];
            float q1 = acc[co][dy][1];
            float y0v = q0 + (q0 > 0.f ? a : (q0 < 0.f ? -a : 0.f));
            float y1v = q1 + (q1 > 0.f ? a : (q1 < 0.f ? -a : 0.f));
            float2 pk; pk.x = y0v; pk.y = y1v;
            *reinterpret_cast<float2*>(&y[cb_off + ((gy0 + dy) << 8) + gx0]) = pk;
            s1 += (double)y0v + (double)y1v;
            s2 += (double)y0v * (double)y0v + (double)y1v * (double)y1v;
        }
    }
    #pragma unroll
    for (int off = 32; off; off >>= 1) {
        s1 += __shfl_down(s1, off);
        s2 += __shfl_down(s2, off);
    }
    const int wid = tid >> 6;
    if ((tid & 63) == 0) { red[wid][0] = s1; red[wid][1] = s2; }
    __syncthreads();
    if (tid == 0) {
        partials[b * 2]     = red[0][0] + red[1][0] + red[2][0] + red[3][0];
        partials[b * 2 + 1] = red[0][1] + red[1][1] + red[2][1] + red[3][1];
    }
}

// ---------------------------------------------------------------------------
// Kernel D: fused stats + norm-affine + gelu (R22-proven).
// ---------------------------------------------------------------------------
__global__ __launch_bounds__(256) void finalize_kernel(float* __restrict__ y,
                                                       const double* __restrict__ partials,
                                                       const float* __restrict__ gnw,
                                                       const float* __restrict__ gnb) {
    const int tid = threadIdx.x;
    double s1 = 0.0, s2 = 0.0;
    for (int i = tid; i < CONV_BLOCKS; i += 256) {
        s1 += partials[2 * i];
        s2 += partials[2 * i + 1];
    }
    #pragma unroll
    for (int off = 32; off; off >>= 1) {
        s1 += __shfl_down(s1, off);
        s2 += __shfl_down(s2, off);
    }
    __shared__ double red[4][2];
    const int wid = tid >> 6;
    if ((tid & 63) == 0) { red[wid][0] = s1; red[wid][1] = s2; }
    __syncthreads();
    const double a1 = red[0][0] + red[1][0] + red[2][0] + red[3][0];
    const double a2 = red[0][1] + red[1][1] + red[2][1] + red[3][1];
    const double mean_d = a1 / (double)N_TOT;
    const double var = a2 / (double)N_TOT - mean_d * mean_d;
    const float mean = (float)mean_d;
    const float istd = (float)(1.0 / sqrt(var + 1e-5));

    const int i = blockIdx.x * 256 + tid;     // float4 index
    const int c = i >> 14;
    const float scale = gnw[c] * istd;
    const float shift = gnb[c] - mean * scale;
    float4 v = reinterpret_cast<float4*>(y)[i];
    v.x = gelu_f(fmaf(v.x, scale, shift));
    v.y = gelu_f(fmaf(v.y, scale, shift));
    v.z = gelu_f(fmaf(v.z, scale, shift));
    v.w = gelu_f(fmaf(v.w, scale, shift));
    reinterpret_cast<float4*>(y)[i] = v;
}

extern "C" void kernel_launch(void* const* d_in, const int* in_sizes, int n_in,
                              void* d_out, int out_size, void* d_ws, size_t ws_size,
                              hipStream_t stream) {
    const float* x   = (const float*)d_in[0];
    const float* cw  = (const float*)d_in[1];
    const float* cb  = (const float*)d_in[2];
    const float* bp  = (const float*)d_in[3];
    const float* Wm  = (const float*)d_in[4];
    const float* gnw = (const float*)d_in[5];
    const float* gnb = (const float*)d_in[6];
    float* out = (float*)d_out;

    char* ws = (char*)d_ws;
    float* alpha     = (float*)ws;                 // 64 floats
    double* partials = (double*)(ws + 512);        // CONV_BLOCKS*2 doubles

    if (ws_size >= (size_t)WS_PAD_OFF + PAD_BYTES) {
        float* xpad = (float*)(ws + WS_PAD_OFF);   // padded x copy (17.97MB)
        prep_kernel<<<16 + PAD_GRID, 256, 0, stream>>>(x, bp, Wm, alpha, xpad);
        conv_kernel<<<CONV_BLOCKS, 256, 0, stream>>>(xpad, cw, cb, alpha, out, partials);
    } else {
        float* zbuf = (float*)(ws + 32768);        // 256B zero page
        hipMemsetAsync(zbuf, 0, 256, stream);
        prep_kernel<<<16, 256, 0, stream>>>(x, bp, Wm, alpha, nullptr);
        conv_fb<<<CONV_BLOCKS, 256, 0, stream>>>(x, cw, cb, alpha, zbuf, out, partials);
    }

    finalize_kernel<<<4096, 256, 0, stream>>>(out, partials, gnw, gnb);
}

// Round 24
// 88.098 us; speedup vs baseline: 1.2259x; 1.2259x over previous
//
#include <hip/hip_runtime.h>
#include <math.h>

#define N_TOT 4194304      // 64*256*256
#define CONV_BLOCKS 1024   // 16 co-groups x 64 tiles (32x32)
#define XS_DW 5120         // 1280 chunks x 4 dw (junk: per-row pad + tail)
#define RSTRIDE 148        // LDS row stride (dw)
#define PITCH 272          // padded x row pitch (dwords), 16B aligned
#define PROWS 258          // padded rows (-1..256)
#define PCI (PROWS * PITCH)        // 70176 dwords per channel
#define PAD_TOT (64 * PCI)         // 4491264 dwords
#define PAD_BYTES (PAD_TOT * 4)    // 17965056 B
#define WS_PAD_OFF 32768
#define PAD_GRID (PAD_TOT / 256)   // 17544

__device__ __forceinline__ float sgnf(float x) {
    return x > 0.f ? 1.f : (x < 0.f ? -1.f : 0.f);
}

__device__ __forceinline__ float gelu_f(float v) {
    const float c0 = 0.7978845608028654f;
    float inner = c0 * fmaf(0.044715f * v, v * v, v);
    return 0.5f * v * (1.f + tanhf(inner));
}

// async HBM->LDS. LDS dest = wave-uniform base + lane*width; full waves only.
__device__ __forceinline__ void gll4(const float* g, float* l) {
    __builtin_amdgcn_global_load_lds((const __attribute__((address_space(1))) void*)g,
                                     (__attribute__((address_space(3))) void*)l, 4, 0, 0);
}
__device__ __forceinline__ void gll16(const float* g, float* l) {
    __builtin_amdgcn_global_load_lds((const __attribute__((address_space(1))) void*)g,
                                     (__attribute__((address_space(3))) void*)l, 16, 0, 0);
}

// ---------------------------------------------------------------------------
// Kernel PREP: blocks 0..15 = alpha (4 channels each, 1 wave per channel);
// blocks 16.. = zero-padded copy of x into ws.
// alpha: sign(q*bp) factors; sign(W@(s*v)) = s*sign(W@v) for s=+-1, so the
// 5-iter Hopfield recurrence is pixel-independent: v <- sign(W_c v).
// ---------------------------------------------------------------------------
__global__ __launch_bounds__(256) void prep_kernel(const float* __restrict__ x,
                                                   const float* __restrict__ bp,
                                                   const float* __restrict__ Wm,
                                                   float* __restrict__ alpha,
                                                   float* __restrict__ pad) {
    const int b = blockIdx.x;
    const int tid = threadIdx.x;
    __shared__ float v[4][64];

    if (b < 16) {
        const int g = tid >> 6;               // wave id = channel sub-index
        const int d = tid & 63;
        const int c = b * 4 + g;
        float bpv = bp[c * 64 + d];
        v[g][d] = sgnf(bpv);
        __syncthreads();
        const float* row = Wm + c * 4096 + d * 64;
        for (int it = 0; it < 5; ++it) {
            float s = 0.f;
            #pragma unroll
            for (int e = 0; e < 64; ++e) s = fmaf(row[e], v[g][e], s);
            __syncthreads();
            v[g][d] = sgnf(s);
            __syncthreads();
        }
        float val = bpv * v[g][d];
        #pragma unroll
        for (int off = 32; off; off >>= 1) val += __shfl_down(val, off);
        if (d == 0) alpha[c] = val;
    } else {
        const int idx = (b - 16) * 256 + tid; // < PAD_TOT (exact)
        const int ci = idx / PCI;
        int rem = idx - ci * PCI;
        const int py = rem / PITCH;
        const int px = rem - py * PITCH;
        float val = 0.f;
        if (py >= 1 && py <= 256 && px >= 1 && px <= 256)
            val = x[(ci << 16) + ((py - 1) << 8) + (px - 1)];
        pad[idx] = val;
    }
}

#define LOAD_T(T, XSC, CIOFF)                                                 \
    {                                                                         \
        _Pragma("unroll")                                                     \
        for (int rr = 0; rr < 4; ++rr) {                                      \
            const int off_ = lrow + rr * RSTRIDE + (CIOFF);                   \
            float2 a_ = *reinterpret_cast<const float2*>(&(XSC)[off_]);       \
            float2 b_ = *reinterpret_cast<const float2*>(&(XSC)[off_ + 2]);   \
            T[rr][0] = a_.x; T[rr][1] = a_.y; T[rr][2] = b_.x; T[rr][3] = b_.y;\
        }                                                                     \
    }

#define FMA_CI(T, WP)                                                         \
    {                                                                         \
        _Pragma("unroll")                                                     \
        for (int co = 0; co < 4; ++co) {                                      \
            const float* w_ = (WP) + co * 576;                                \
            _Pragma("unroll")                                                 \
            for (int ky = 0; ky < 3; ++ky)                                    \
                _Pragma("unroll")                                             \
                for (int kx = 0; kx < 3; ++kx) {                              \
                    float wv_ = w_[ky * 3 + kx];                              \
                    _Pragma("unroll")                                         \
                    for (int dy = 0; dy < 2; ++dy)                            \
                        _Pragma("unroll")                                     \
                        for (int j = 0; j < 2; ++j)                           \
                            acc[co][dy][j] = fmaf(wv_, T[dy + ky][kx + j],    \
                                                  acc[co][dy][j]);            \
                }                                                             \
        }                                                                     \
    }

// ---------------------------------------------------------------------------
// Kernel B: 3x3 SAME conv (fp32) + bias + fused y = q + sgn(q)*alpha[c].
// R22-proven: padded-x gll16 staging (5 unmasked slots), double-buffered
// prefetch, tA/tB ci pipeline, 2x2 paired micro-tile, wave-uniform weights.
// ---------------------------------------------------------------------------
__global__ __launch_bounds__(256, 2) void conv_kernel(const float* __restrict__ xp,
                                                      const float* __restrict__ cw,
                                                      const float* __restrict__ cb,
                                                      const float* __restrict__ alpha,
                                                      float* __restrict__ y,
                                                      double* __restrict__ partials) {
    const int tid = threadIdx.x;
    const int b = blockIdx.x;
    const int tile = b & 63;
    const int cog = b >> 6;                   // 4 output channels per group
    const int bx = tile & 7, by = tile >> 3;  // 8x8 tiles of 32x32
    const int tx = tid & 15, ty = tid >> 4;   // cols 2tx,2tx+1; rows 2ty,2ty+1

    __shared__ float xs[2][XS_DW];            // [buf][r*148 + ci*36 + c]
    double* red = (double*)&xs[1][5032];      // 8 doubles in buf1 junk tail

    int goff[5];
    #pragma unroll
    for (int i = 0; i < 5; ++i) {
        int c4 = i * 256 + tid;               // chunk id < 1280
        int r = c4 / 37;                      // 37 chunks per LDS row
        int rem = c4 - r * 37;
        int ci = rem / 9;
        int cc = rem - ci * 9;
        bool junk = (rem >= 36) || (c4 >= 1258);
        int g = ci * PCI + ((by << 5) + r) * PITCH + (bx << 5) + cc * 4;
        goff[i] = junk ? 0 : g;               // junk chunks read pad base
    }

    float acc[4][2][2];
    #pragma unroll
    for (int co = 0; co < 4; ++co) {
        float bias = cb[cog * 4 + co];
        acc[co][0][0] = bias; acc[co][0][1] = bias;
        acc[co][1][0] = bias; acc[co][1][1] = bias;
    }

    #pragma unroll
    for (int i = 0; i < 5; ++i)
        gll16(xp + goff[i], &xs[0][(i * 256 + tid) * 4]);
    __syncthreads();                          // vmcnt drain -> slab 0 ready

    const int lrow = (2 * ty) * RSTRIDE + 2 * tx;
    const float* wbase = cw + cog * 4 * 576;

    float tA[4][4], tB[4][4];

    for (int s = 0; s < 16; ++s) {
        const int cur = s & 1;
        if (s < 15) {
            const float* xb = xp + (s + 1) * (4 * PCI);
            #pragma unroll
            for (int i = 0; i < 5; ++i)
                gll16(xb + goff[i], &xs[cur ^ 1][(i * 256 + tid) * 4]);
        }

        const float* xsc = xs[cur];
        const float* wp = wbase + (s * 4) * 9;

        LOAD_T(tA, xsc, 0)
        LOAD_T(tB, xsc, 36)
        FMA_CI(tA, wp)
        LOAD_T(tA, xsc, 72)
        FMA_CI(tB, wp + 9)
        LOAD_T(tB, xsc, 108)
        FMA_CI(tA, wp + 18)
        FMA_CI(tB, wp + 27)

        __syncthreads();
    }

    // epilogue: y = q + sgn(q)*alpha, aligned float2 stores + f64 sums
    double s1 = 0.0, s2 = 0.0;
    const int gx0 = (bx << 5) + 2 * tx;
    const int gy0 = (by << 5) + 2 * ty;
    #pragma unroll
    for (int co = 0; co < 4; ++co) {
        float a = alpha[cog * 4 + co];
        const int cb_off = (cog * 4 + co) << 16;
        #pragma unroll
        for (int dy = 0; dy < 2; ++dy) {
            float q0 = acc[co][dy][0];
            float q1 = acc[co][dy][1];
            float y0v = q0 + (q0 > 0.f ? a : (q0 < 0.f ? -a : 0.f));
            float y1v = q1 + (q1 > 0.f ? a : (q1 < 0.f ? -a : 0.f));
            float2 pk; pk.x = y0v; pk.y = y1v;
            *reinterpret_cast<float2*>(&y[cb_off + ((gy0 + dy) << 8) + gx0]) = pk;
            s1 += (double)y0v + (double)y1v;
            s2 += (double)y0v * (double)y0v + (double)y1v * (double)y1v;
        }
    }
    #pragma unroll
    for (int off = 32; off; off >>= 1) {
        s1 += __shfl_down(s1, off);
        s2 += __shfl_down(s2, off);
    }
    const int wid = tid >> 6;
    if ((tid & 63) == 0) { red[wid * 2] = s1; red[wid * 2 + 1] = s2; }
    __syncthreads();
    if (tid == 0) {
        partials[b * 2]     = red[0] + red[2] + red[4] + red[6];
        partials[b * 2 + 1] = red[1] + red[3] + red[5] + red[7];
    }
}

// ---------------------------------------------------------------------------
// Fallback conv (no padded x) if ws is too small: R15 path.
// ---------------------------------------------------------------------------
__global__ __launch_bounds__(256, 2) void conv_fb(const float* __restrict__ x,
                                                  const float* __restrict__ cw,
                                                  const float* __restrict__ cb,
                                                  const float* __restrict__ alpha,
                                                  const float* __restrict__ zbuf,
                                                  float* __restrict__ y,
                                                  double* __restrict__ partials) {
    const int tid = threadIdx.x;
    const int b = blockIdx.x;
    const int tile = b & 63;
    const int cog = b >> 6;
    const int bx = tile & 7, by = tile >> 3;
    const int tx = tid & 15, ty = tid >> 4;

    __shared__ float xs[2][4864];
    __shared__ double red[4][2];

    int voff[19];
    unsigned vmask = 0u;
    #pragma unroll
    for (int i = 0; i < 19; ++i) {
        int idx = i * 256 + tid;
        int r = idx / 136;
        int rem = idx - r * 136;
        int ci = rem / 34;
        int c = rem - ci * 34;
        int gy = (by << 5) - 1 + r;
        int gx = (bx << 5) + c - 1;
        bool ok = (idx < 4624) && ((unsigned)gy < 256u) && ((unsigned)gx < 256u);
        voff[i] = (ci << 16) + (gy << 8) + gx;
        if (ok) vmask |= (1u << i);
    }

    float acc[4][2][2];
    #pragma unroll
    for (int co = 0; co < 4; ++co) {
        float bias = cb[cog * 4 + co];
        acc[co][0][0] = bias; acc[co][0][1] = bias;
        acc[co][1][0] = bias; acc[co][1][1] = bias;
    }

    #pragma unroll
    for (int i = 0; i < 19; ++i) {
        const float* src = (vmask & (1u << i)) ? (x + voff[i]) : zbuf;
        gll4(src, &xs[0][i * 256 + tid]);
    }
    __syncthreads();

    const int lrow2 = (2 * ty) * 136 + 2 * tx;
    const float* wbase = cw + cog * 4 * 576;

    for (int s = 0; s < 16; ++s) {
        const int cur = s & 1;
        if (s < 15) {
            const float* xb = x + ((s + 1) << 18);
            #pragma unroll
            for (int i = 0; i < 19; ++i) {
                const float* src = (vmask & (1u << i)) ? (xb + voff[i]) : zbuf;
                gll4(src, &xs[cur ^ 1][i * 256 + tid]);
            }
        }
        const float* xsc = xs[cur];
        #pragma unroll
        for (int ci = 0; ci < 4; ++ci) {
            float t[4][4];
            #pragma unroll
            for (int rr = 0; rr < 4; ++rr) {
                const int off = lrow2 + rr * 136 + ci * 34;
                float2 a = *reinterpret_cast<const float2*>(&xsc[off]);
                float2 bb = *reinterpret_cast<const float2*>(&xsc[off + 2]);
                t[rr][0] = a.x; t[rr][1] = a.y; t[rr][2] = bb.x; t[rr][3] = bb.y;
            }
            const float* wp = wbase + (s * 4 + ci) * 9;
            #pragma unroll
            for (int co = 0; co < 4; ++co) {
                const float* w = wp + co * 576;
                #pragma unroll
                for (int ky = 0; ky < 3; ++ky)
                    #pragma unroll
                    for (int kx = 0; kx < 3; ++kx) {
                        float wv = w[ky * 3 + kx];
                        #pragma unroll
                        for (int dy = 0; dy < 2; ++dy)
                            #pragma unroll
                            for (int j = 0; j < 2; ++j)
                                acc[co][dy][j] = fmaf(wv, t[dy + ky][kx + j], acc[co][dy][j]);
                    }
            }
        }
        __syncthreads();
    }

    double s1 = 0.0, s2 = 0.0;
    const int gx0 = (bx << 5) + 2 * tx;
    const int gy0 = (by << 5) + 2 * ty;
    #pragma unroll
    for (int co = 0; co < 4; ++co) {
        float a = alpha[cog * 4 + co];
        const int cb_off = (cog * 4 + co) << 16;
        #pragma unroll
        for (int dy = 0; dy < 2; ++dy) {
            float q0 = acc[co][dy][0];
            float q1 = acc[co][dy][1];
            float y0v = q0 + (q0 > 0.f ? a : (q0 < 0.f ? -a : 0.f));
            float y1v = q1 + (q1 > 0.f ? a : (q1 < 0.f ? -a : 0.f));
            float2 pk; pk.x = y0v; pk.y = y1v;
            *reinterpret_cast<float2*>(&y[cb_off + ((gy0 + dy) << 8) + gx0]) = pk;
            s1 += (double)y0v + (double)y1v;
            s2 += (double)y0v * (double)y0v + (double)y1v * (double)y1v;
        }
    }
    #pragma unroll
    for (int off = 32; off; off >>= 1) {
        s1 += __shfl_down(s1, off);
        s2 += __shfl_down(s2, off);
    }
    const int wid = tid >> 6;
    if ((tid & 63) == 0) { red[wid][0] = s1; red[wid][1] = s2; }
    __syncthreads();
    if (tid == 0) {
        partials[b * 2]     = red[0][0] + red[1][0] + red[2][0] + red[3][0];
        partials[b * 2 + 1] = red[0][1] + red[1][1] + red[2][1] + red[3][1];
    }
}

// ---------------------------------------------------------------------------
// Kernel D: fused stats + norm-affine + gelu. 1024 blocks x 4 float4/thread
// (grid-stride): partials L2 traffic 4096->1024 block-reads (64->16MB).
// ---------------------------------------------------------------------------
__global__ __launch_bounds__(256) void finalize_kernel(float* __restrict__ y,
                                                       const double* __restrict__ partials,
                                                       const float* __restrict__ gnw,
                                                       const float* __restrict__ gnb) {
    const int tid = threadIdx.x;
    double s1 = 0.0, s2 = 0.0;
    for (int i = tid; i < CONV_BLOCKS; i += 256) {
        s1 += partials[2 * i];
        s2 += partials[2 * i + 1];
    }
    #pragma unroll
    for (int off = 32; off; off >>= 1) {
        s1 += __shfl_down(s1, off);
        s2 += __shfl_down(s2, off);
    }
    __shared__ double red[4][2];
    const int wid = tid >> 6;
    if ((tid & 63) == 0) { red[wid][0] = s1; red[wid][1] = s2; }
    __syncthreads();
    const double a1 = red[0][0] + red[1][0] + red[2][0] + red[3][0];
    const double a2 = red[0][1] + red[1][1] + red[2][1] + red[3][1];
    const double mean_d = a1 / (double)N_TOT;
    const double var = a2 / (double)N_TOT - mean_d * mean_d;
    const float mean = (float)mean_d;
    const float istd = (float)(1.0 / sqrt(var + 1e-5));

    const int base = blockIdx.x * 1024 + tid;     // 4 float4 per thread
    #pragma unroll
    for (int k = 0; k < 4; ++k) {
        const int i = base + k * 256;             // float4 index
        const int c = i >> 14;
        const float scale = gnw[c] * istd;
        const float shift = gnb[c] - mean * scale;
        float4 v = reinterpret_cast<float4*>(y)[i];
        v.x = gelu_f(fmaf(v.x, scale, shift));
        v.y = gelu_f(fmaf(v.y, scale, shift));
        v.z = gelu_f(fmaf(v.z, scale, shift));
        v.w = gelu_f(fmaf(v.w, scale, shift));
        reinterpret_cast<float4*>(y)[i] = v;
    }
}

extern "C" void kernel_launch(void* const* d_in, const int* in_sizes, int n_in,
                              void* d_out, int out_size, void* d_ws, size_t ws_size,
                              hipStream_t stream) {
    const float* x   = (const float*)d_in[0];
    const float* cw  = (const float*)d_in[1];
    const float* cb  = (const float*)d_in[2];
    const float* bp  = (const float*)d_in[3];
    const float* Wm  = (const float*)d_in[4];
    const float* gnw = (const float*)d_in[5];
    const float* gnb = (const float*)d_in[6];
    float* out = (float*)d_out;

    char* ws = (char*)d_ws;
    float* alpha     = (float*)ws;                 // 64 floats
    double* partials = (double*)(ws + 512);        // CONV_BLOCKS*2 doubles

    if (ws_size >= (size_t)WS_PAD_OFF + PAD_BYTES) {
        float* xpad = (float*)(ws + WS_PAD_OFF);   // padded x copy (17.97MB)
        prep_kernel<<<16 + PAD_GRID, 256, 0, stream>>>(x, bp, Wm, alpha, xpad);
        conv_kernel<<<CONV_BLOCKS, 256, 0, stream>>>(xpad, cw, cb, alpha, out, partials);
    } else {
        float* zbuf = (float*)(ws + 32768);        // 256B zero page
        hipMemsetAsync(zbuf, 0, 256, stream);
        prep_kernel<<<16, 256, 0, stream>>>(x, bp, Wm, alpha, nullptr);
        conv_fb<<<CONV_BLOCKS, 256, 0, stream>>>(x, cw, cb, alpha, zbuf, out, partials);
    }

    finalize_kernel<<<1024, 256, 0, stream>>>(out, partials, gnw, gnb);
}

// Round 25
// 86.988 us; speedup vs baseline: 1.2415x; 1.0128x over previous
//
#include <hip/hip_runtime.h>
#include <math.h>

#define N_TOT 4194304      // 64*256*256
#define CONV_BLOCKS 1024   // 16 co-groups x 64 tiles (32x32)
#define XS_DW 5120         // 1280 chunks x 4 dw (junk: per-row pad + tail)
#define RSTRIDE 148        // LDS row stride (dw)
#define PITCH 272          // padded x row pitch (dwords), 16B aligned
#define PROWS 258          // padded rows (-1..256)
#define PCI (PROWS * PITCH)        // 70176 dwords per channel
#define PAD_TOT (64 * PCI)         // 4491264 dwords
#define PAD_BYTES (PAD_TOT * 4)    // 17965056 B
#define WS_PAD_OFF 32768
#define PAD_GRID4 (PAD_TOT / 1024) // 4386 blocks (float4 granularity, exact)

__device__ __forceinline__ float sgnf(float x) {
    return x > 0.f ? 1.f : (x < 0.f ? -1.f : 0.f);
}

__device__ __forceinline__ float gelu_f(float v) {
    const float c0 = 0.7978845608028654f;
    float inner = c0 * fmaf(0.044715f * v, v * v, v);
    return 0.5f * v * (1.f + tanhf(inner));
}

// async HBM->LDS. LDS dest = wave-uniform base + lane*width; full waves only.
__device__ __forceinline__ void gll4(const float* g, float* l) {
    __builtin_amdgcn_global_load_lds((const __attribute__((address_space(1))) void*)g,
                                     (__attribute__((address_space(3))) void*)l, 4, 0, 0);
}
__device__ __forceinline__ void gll16(const float* g, float* l) {
    __builtin_amdgcn_global_load_lds((const __attribute__((address_space(1))) void*)g,
                                     (__attribute__((address_space(3))) void*)l, 16, 0, 0);
}

// ---------------------------------------------------------------------------
// Kernel PREP: blocks 0..15 = alpha (4 channels each, 1 wave per channel);
// blocks 16.. = zero-padded copy of x into ws, float4 STORES (4x fewer write
// instrs than R24's scalar path; 16B/lane = coalescing sweet spot).
// alpha: sign(q*bp) factors; sign(W@(s*v)) = s*sign(W@v) for s=+-1, so the
// 5-iter Hopfield recurrence is pixel-independent: v <- sign(W_c v).
// ---------------------------------------------------------------------------
__global__ __launch_bounds__(256) void prep_kernel(const float* __restrict__ x,
                                                   const float* __restrict__ bp,
                                                   const float* __restrict__ Wm,
                                                   float* __restrict__ alpha,
                                                   float* __restrict__ pad) {
    const int b = blockIdx.x;
    const int tid = threadIdx.x;
    __shared__ float v[4][64];

    if (b < 16) {
        const int g = tid >> 6;               // wave id = channel sub-index
        const int d = tid & 63;
        const int c = b * 4 + g;
        float bpv = bp[c * 64 + d];
        v[g][d] = sgnf(bpv);
        __syncthreads();
        const float* row = Wm + c * 4096 + d * 64;
        for (int it = 0; it < 5; ++it) {
            float s = 0.f;
            #pragma unroll
            for (int e = 0; e < 64; ++e) s = fmaf(row[e], v[g][e], s);
            __syncthreads();
            v[g][d] = sgnf(s);
            __syncthreads();
        }
        float val = bpv * v[g][d];
        #pragma unroll
        for (int off = 32; off; off >>= 1) val += __shfl_down(val, off);
        if (d == 0) alpha[c] = val;
    } else {
        const int idx4 = (b - 16) * 256 + tid;   // float4 id < PAD_TOT/4
        const int ci = idx4 / (PCI / 4);
        int rem4 = idx4 - ci * (PCI / 4);
        const int py = rem4 / (PITCH / 4);
        const int px0 = (rem4 - py * (PITCH / 4)) * 4;
        float4 o;
        float* op = &o.x;
        const bool rowok = (py >= 1 && py <= 256);
        const int xrow = (ci << 16) + ((py - 1) << 8);
        #pragma unroll
        for (int k = 0; k < 4; ++k) {
            int px = px0 + k;
            op[k] = (rowok && px >= 1 && px <= 256) ? x[xrow + px - 1] : 0.f;
        }
        reinterpret_cast<float4*>(pad)[idx4] = o;
    }
}

#define LOAD_T(T, XSC, CIOFF)                                                 \
    {                                                                         \
        _Pragma("unroll")                                                     \
        for (int rr = 0; rr < 4; ++rr) {                                      \
            const int off_ = lrow + rr * RSTRIDE + (CIOFF);                   \
            float2 a_ = *reinterpret_cast<const float2*>(&(XSC)[off_]);       \
            float2 b_ = *reinterpret_cast<const float2*>(&(XSC)[off_ + 2]);   \
            T[rr][0] = a_.x; T[rr][1] = a_.y; T[rr][2] = b_.x; T[rr][3] = b_.y;\
        }                                                                     \
    }

#define FMA_CI(T, WP)                                                         \
    {                                                                         \
        _Pragma("unroll")                                                     \
        for (int co = 0; co < 4; ++co) {                                      \
            const float* w_ = (WP) + co * 576;                                \
            _Pragma("unroll")                                                 \
            for (int ky = 0; ky < 3; ++ky)                                    \
                _Pragma("unroll")                                             \
                for (int kx = 0; kx < 3; ++kx) {                              \
                    float wv_ = w_[ky * 3 + kx];                              \
                    _Pragma("unroll")                                         \
                    for (int dy = 0; dy < 2; ++dy)                            \
                        _Pragma("unroll")                                     \
                        for (int j = 0; j < 2; ++j)                           \
                            acc[co][dy][j] = fmaf(wv_, T[dy + ky][kx + j],    \
                                                  acc[co][dy][j]);            \
                }                                                             \
        }                                                                     \
    }

// ---------------------------------------------------------------------------
// Kernel B: 3x3 SAME conv (fp32) + bias + fused y = q + sgn(q)*alpha[c].
// R22/R24-proven: padded-x gll16 staging (5 unmasked slots), double-buffered
// prefetch, tA/tB ci pipeline, 2x2 paired micro-tile, wave-uniform weights.
// ---------------------------------------------------------------------------
__global__ __launch_bounds__(256, 2) void conv_kernel(const float* __restrict__ xp,
                                                      const float* __restrict__ cw,
                                                      const float* __restrict__ cb,
                                                      const float* __restrict__ alpha,
                                                      float* __restrict__ y,
                                                      double* __restrict__ partials) {
    const int tid = threadIdx.x;
    const int b = blockIdx.x;
    const int tile = b & 63;
    const int cog = b >> 6;                   // 4 output channels per group
    const int bx = tile & 7, by = tile >> 3;  // 8x8 tiles of 32x32
    const int tx = tid & 15, ty = tid >> 4;   // cols 2tx,2tx+1; rows 2ty,2ty+1

    __shared__ float xs[2][XS_DW];            // [buf][r*148 + ci*36 + c]
    double* red = (double*)&xs[1][5032];      // 8 doubles in buf1 junk tail

    int goff[5];
    #pragma unroll
    for (int i = 0; i < 5; ++i) {
        int c4 = i * 256 + tid;               // chunk id < 1280
        int r = c4 / 37;                      // 37 chunks per LDS row
        int rem = c4 - r * 37;
        int ci = rem / 9;
        int cc = rem - ci * 9;
        bool junk = (rem >= 36) || (c4 >= 1258);
        int g = ci * PCI + ((by << 5) + r) * PITCH + (bx << 5) + cc * 4;
        goff[i] = junk ? 0 : g;               // junk chunks read pad base
    }

    float acc[4][2][2];
    #pragma unroll
    for (int co = 0; co < 4; ++co) {
        float bias = cb[cog * 4 + co];
        acc[co][0][0] = bias; acc[co][0][1] = bias;
        acc[co][1][0] = bias; acc[co][1][1] = bias;
    }

    #pragma unroll
    for (int i = 0; i < 5; ++i)
        gll16(xp + goff[i], &xs[0][(i * 256 + tid) * 4]);
    __syncthreads();                          // vmcnt drain -> slab 0 ready

    const int lrow = (2 * ty) * RSTRIDE + 2 * tx;
    const float* wbase = cw + cog * 4 * 576;

    float tA[4][4], tB[4][4];

    for (int s = 0; s < 16; ++s) {
        const int cur = s & 1;
        if (s < 15) {
            const float* xb = xp + (s + 1) * (4 * PCI);
            #pragma unroll
            for (int i = 0; i < 5; ++i)
                gll16(xb + goff[i], &xs[cur ^ 1][(i * 256 + tid) * 4]);
        }

        const float* xsc = xs[cur];
        const float* wp = wbase + (s * 4) * 9;

        LOAD_T(tA, xsc, 0)
        LOAD_T(tB, xsc, 36)
        FMA_CI(tA, wp)
        LOAD_T(tA, xsc, 72)
        FMA_CI(tB, wp + 9)
        LOAD_T(tB, xsc, 108)
        FMA_CI(tA, wp + 18)
        FMA_CI(tB, wp + 27)

        __syncthreads();
    }

    // epilogue: y = q + sgn(q)*alpha, aligned float2 stores + f64 sums
    double s1 = 0.0, s2 = 0.0;
    const int gx0 = (bx << 5) + 2 * tx;
    const int gy0 = (by << 5) + 2 * ty;
    #pragma unroll
    for (int co = 0; co < 4; ++co) {
        float a = alpha[cog * 4 + co];
        const int cb_off = (cog * 4 + co) << 16;
        #pragma unroll
        for (int dy = 0; dy < 2; ++dy) {
            float q0 = acc[co][dy][0];
            float q1 = acc[co][dy][1];
            float y0v = q0 + (q0 > 0.f ? a : (q0 < 0.f ? -a : 0.f));
            float y1v = q1 + (q1 > 0.f ? a : (q1 < 0.f ? -a : 0.f));
            float2 pk; pk.x = y0v; pk.y = y1v;
            *reinterpret_cast<float2*>(&y[cb_off + ((gy0 + dy) << 8) + gx0]) = pk;
            s1 += (double)y0v + (double)y1v;
            s2 += (double)y0v * (double)y0v + (double)y1v * (double)y1v;
        }
    }
    #pragma unroll
    for (int off = 32; off; off >>= 1) {
        s1 += __shfl_down(s1, off);
        s2 += __shfl_down(s2, off);
    }
    const int wid = tid >> 6;
    if ((tid & 63) == 0) { red[wid * 2] = s1; red[wid * 2 + 1] = s2; }
    __syncthreads();
    if (tid == 0) {
        partials[b * 2]     = red[0] + red[2] + red[4] + red[6];
        partials[b * 2 + 1] = red[1] + red[3] + red[5] + red[7];
    }
}

// ---------------------------------------------------------------------------
// Fallback conv (no padded x) if ws is too small: R15 path.
// ---------------------------------------------------------------------------
__global__ __launch_bounds__(256, 2) void conv_fb(const float* __restrict__ x,
                                                  const float* __restrict__ cw,
                                                  const float* __restrict__ cb,
                                                  const float* __restrict__ alpha,
                                                  const float* __restrict__ zbuf,
                                                  float* __restrict__ y,
                                                  double* __restrict__ partials) {
    const int tid = threadIdx.x;
    const int b = blockIdx.x;
    const int tile = b & 63;
    const int cog = b >> 6;
    const int bx = tile & 7, by = tile >> 3;
    const int tx = tid & 15, ty = tid >> 4;

    __shared__ float xs[2][4864];
    __shared__ double red[4][2];

    int voff[19];
    unsigned vmask = 0u;
    #pragma unroll
    for (int i = 0; i < 19; ++i) {
        int idx = i * 256 + tid;
        int r = idx / 136;
        int rem = idx - r * 136;
        int ci = rem / 34;
        int c = rem - ci * 34;
        int gy = (by << 5) - 1 + r;
        int gx = (bx << 5) + c - 1;
        bool ok = (idx < 4624) && ((unsigned)gy < 256u) && ((unsigned)gx < 256u);
        voff[i] = (ci << 16) + (gy << 8) + gx;
        if (ok) vmask |= (1u << i);
    }

    float acc[4][2][2];
    #pragma unroll
    for (int co = 0; co < 4; ++co) {
        float bias = cb[cog * 4 + co];
        acc[co][0][0] = bias; acc[co][0][1] = bias;
        acc[co][1][0] = bias; acc[co][1][1] = bias;
    }

    #pragma unroll
    for (int i = 0; i < 19; ++i) {
        const float* src = (vmask & (1u << i)) ? (x + voff[i]) : zbuf;
        gll4(src, &xs[0][i * 256 + tid]);
    }
    __syncthreads();

    const int lrow2 = (2 * ty) * 136 + 2 * tx;
    const float* wbase = cw + cog * 4 * 576;

    for (int s = 0; s < 16; ++s) {
        const int cur = s & 1;
        if (s < 15) {
            const float* xb = x + ((s + 1) << 18);
            #pragma unroll
            for (int i = 0; i < 19; ++i) {
                const float* src = (vmask & (1u << i)) ? (xb + voff[i]) : zbuf;
                gll4(src, &xs[cur ^ 1][i * 256 + tid]);
            }
        }
        const float* xsc = xs[cur];
        #pragma unroll
        for (int ci = 0; ci < 4; ++ci) {
            float t[4][4];
            #pragma unroll
            for (int rr = 0; rr < 4; ++rr) {
                const int off = lrow2 + rr * 136 + ci * 34;
                float2 a = *reinterpret_cast<const float2*>(&xsc[off]);
                float2 bb = *reinterpret_cast<const float2*>(&xsc[off + 2]);
                t[rr][0] = a.x; t[rr][1] = a.y; t[rr][2] = bb.x; t[rr][3] = bb.y;
            }
            const float* wp = wbase + (s * 4 + ci) * 9;
            #pragma unroll
            for (int co = 0; co < 4; ++co) {
                const float* w = wp + co * 576;
                #pragma unroll
                for (int ky = 0; ky < 3; ++ky)
                    #pragma unroll
                    for (int kx = 0; kx < 3; ++kx) {
                        float wv = w[ky * 3 + kx];
                        #pragma unroll
                        for (int dy = 0; dy < 2; ++dy)
                            #pragma unroll
                            for (int j = 0; j < 2; ++j)
                                acc[co][dy][j] = fmaf(wv, t[dy + ky][kx + j], acc[co][dy][j]);
                    }
            }
        }
        __syncthreads();
    }

    double s1 = 0.0, s2 = 0.0;
    const int gx0 = (bx << 5) + 2 * tx;
    const int gy0 = (by << 5) + 2 * ty;
    #pragma unroll
    for (int co = 0; co < 4; ++co) {
        float a = alpha[cog * 4 + co];
        const int cb_off = (cog * 4 + co) << 16;
        #pragma unroll
        for (int dy = 0; dy < 2; ++dy) {
            float q0 = acc[co][dy][0];
            float q1 = acc[co][dy][1];
            float y0v = q0 + (q0 > 0.f ? a : (q0 < 0.f ? -a : 0.f));
            float y1v = q1 + (q1 > 0.f ? a : (q1 < 0.f ? -a : 0.f));
            float2 pk; pk.x = y0v; pk.y = y1v;
            *reinterpret_cast<float2*>(&y[cb_off + ((gy0 + dy) << 8) + gx0]) = pk;
            s1 += (double)y0v + (double)y1v;
            s2 += (double)y0v * (double)y0v + (double)y1v * (double)y1v;
        }
    }
    #pragma unroll
    for (int off = 32; off; off >>= 1) {
        s1 += __shfl_down(s1, off);
        s2 += __shfl_down(s2, off);
    }
    const int wid = tid >> 6;
    if ((tid & 63) == 0) { red[wid][0] = s1; red[wid][1] = s2; }
    __syncthreads();
    if (tid == 0) {
        partials[b * 2]     = red[0][0] + red[1][0] + red[2][0] + red[3][0];
        partials[b * 2 + 1] = red[0][1] + red[1][1] + red[2][1] + red[3][1];
    }
}

// ---------------------------------------------------------------------------
// Kernel D: fused stats + norm-affine + gelu. 1024 blocks x 4 float4/thread.
// ---------------------------------------------------------------------------
__global__ __launch_bounds__(256) void finalize_kernel(float* __restrict__ y,
                                                       const double* __restrict__ partials,
                                                       const float* __restrict__ gnw,
                                                       const float* __restrict__ gnb) {
    const int tid = threadIdx.x;
    double s1 = 0.0, s2 = 0.0;
    for (int i = tid; i < CONV_BLOCKS; i += 256) {
        s1 += partials[2 * i];
        s2 += partials[2 * i + 1];
    }
    #pragma unroll
    for (int off = 32; off; off >>= 1) {
        s1 += __shfl_down(s1, off);
        s2 += __shfl_down(s2, off);
    }
    __shared__ double red[4][2];
    const int wid = tid >> 6;
    if ((tid & 63) == 0) { red[wid][0] = s1; red[wid][1] = s2; }
    __syncthreads();
    const double a1 = red[0][0] + red[1][0] + red[2][0] + red[3][0];
    const double a2 = red[0][1] + red[1][1] + red[2][1] + red[3][1];
    const double mean_d = a1 / (double)N_TOT;
    const double var = a2 / (double)N_TOT - mean_d * mean_d;
    const float mean = (float)mean_d;
    const float istd = (float)(1.0 / sqrt(var + 1e-5));

    const int base = blockIdx.x * 1024 + tid;     // 4 float4 per thread
    #pragma unroll
    for (int k = 0; k < 4; ++k) {
        const int i = base + k * 256;             // float4 index
        const int c = i >> 14;
        const float scale = gnw[c] * istd;
        const float shift = gnb[c] - mean * scale;
        float4 v = reinterpret_cast<float4*>(y)[i];
        v.x = gelu_f(fmaf(v.x, scale, shift));
        v.y = gelu_f(fmaf(v.y, scale, shift));
        v.z = gelu_f(fmaf(v.z, scale, shift));
        v.w = gelu_f(fmaf(v.w, scale, shift));
        reinterpret_cast<float4*>(y)[i] = v;
    }
}

extern "C" void kernel_launch(void* const* d_in, const int* in_sizes, int n_in,
                              void* d_out, int out_size, void* d_ws, size_t ws_size,
                              hipStream_t stream) {
    const float* x   = (const float*)d_in[0];
    const float* cw  = (const float*)d_in[1];
    const float* cb  = (const float*)d_in[2];
    const float* bp  = (const float*)d_in[3];
    const float* Wm  = (const float*)d_in[4];
    const float* gnw = (const float*)d_in[5];
    const float* gnb = (const float*)d_in[6];
    float* out = (float*)d_out;

    char* ws = (char*)d_ws;
    float* alpha     = (float*)ws;                 // 64 floats
    double* partials = (double*)(ws + 512);        // CONV_BLOCKS*2 doubles

    if (ws_size >= (size_t)WS_PAD_OFF + PAD_BYTES) {
        float* xpad = (float*)(ws + WS_PAD_OFF);   // padded x copy (17.97MB)
        prep_kernel<<<16 + PAD_GRID4, 256, 0, stream>>>(x, bp, Wm, alpha, xpad);
        conv_kernel<<<CONV_BLOCKS, 256, 0, stream>>>(xpad, cw, cb, alpha, out, partials);
    } else {
        float* zbuf = (float*)(ws + 32768);        // 256B zero page
        hipMemsetAsync(zbuf, 0, 256, stream);
        prep_kernel<<<16, 256, 0, stream>>>(x, bp, Wm, alpha, nullptr);
        conv_fb<<<CONV_BLOCKS, 256, 0, stream>>>(x, cw, cb, alpha, zbuf, out, partials);
    }

    finalize_kernel<<<1024, 256, 0, stream>>>(out, partials, gnw, gnb);
}